// Round 8
// baseline (722.623 us; speedup 1.0000x reference)
//
#include <hip/hip_runtime.h>
#include <hip/hip_bf16.h>

typedef __attribute__((ext_vector_type(8))) short short8;
typedef __attribute__((ext_vector_type(4))) float f32x4;
typedef __attribute__((ext_vector_type(4))) unsigned short u16x4;

#define D 256

static __device__ __forceinline__ unsigned short f2bf(float f) {
    union { __hip_bfloat16 h; unsigned short u; } v;
    v.h = __float2bfloat16(f);
    return v.u;
}
static __device__ __forceinline__ float bf2f(unsigned short h) {
    union { unsigned u; float f; } v; v.u = ((unsigned)h) << 16;
    return v.f;
}

// Pack W [K x 256] row-major f32 -> bf16 fragment-ready layout.
__global__ void pack_w_kernel(const float* __restrict__ W, unsigned short* __restrict__ dst,
                              int log2nkk, int total) {
    int p = blockIdx.x * blockDim.x + threadIdx.x;
    if (p >= total) return;
    int j     = p & 7;
    int lane  = (p >> 3) & 63;
    int kk    = (p >> 9) & ((1 << log2nkk) - 1);
    int ntile = p >> (9 + log2nkk);
    int k = kk * 32 + ((lane >> 4) * 8) + j;
    int n = ntile * 16 + (lane & 15);
    dst[p] = f2bf(W[k * D + n]);
}

__global__ void clear_flags_kernel(unsigned* __restrict__ f, int n) {
    int i = blockIdx.x * blockDim.x + threadIdx.x;
    if (i < n) f[i] = 0u;
}

__global__ void scatter_flags_kernel(const int* __restrict__ kidx,
                                     unsigned char* __restrict__ flags, int m) {
    int i = blockIdx.x * blockDim.x + threadIdx.x;
    if (i < m) flags[kidx[i]] = 1;
}

// projall[r] = relu(cfg[r] @ Wu + bu) as bf16, row-major [N_CFG][256].
__global__ __launch_bounds__(256, 5) void projall_kernel(
    const float* __restrict__ cfg, const unsigned short* __restrict__ WuP,
    const float* __restrict__ bu, unsigned short* __restrict__ projall, int ncfg)
{
    __shared__ unsigned short Aub[64 * D];
    char* aubB = (char*)Aub;
    const int t = threadIdx.x, lane = t & 63, wid = t >> 6;
    const int lr = lane & 15, lk = lane >> 4;
    const int base = blockIdx.x * 64;

    #pragma unroll
    for (int i = 0; i < 16; ++i) {
        int row = wid * 16 + i;
        int r = base + row;
        f32x4 u = (f32x4){0.f, 0.f, 0.f, 0.f};
        if (r < ncfg) u = *(const f32x4*)(cfg + (size_t)r * D + lane * 4);
        int boff = (lane * 8) ^ ((row & 7) << 4);
        u16x4 hu;
        hu.x = f2bf(u.x); hu.y = f2bf(u.y); hu.z = f2bf(u.z); hu.w = f2bf(u.w);
        *(u16x4*)(aubB + row * 512 + boff) = hu;
    }
    __syncthreads();

    f32x4 acc[4][4];
    #pragma unroll
    for (int fm = 0; fm < 4; ++fm)
        #pragma unroll
        for (int fn = 0; fn < 4; ++fn)
            acc[fm][fn] = (f32x4){0.f, 0.f, 0.f, 0.f};

    #pragma unroll
    for (int kk = 0; kk < 8; ++kk) {
        short8 a[4], b[4];
        #pragma unroll
        for (int fm = 0; fm < 4; ++fm) {
            int row = fm * 16 + lr;
            int boff = (kk * 64 + lk * 16) ^ ((row & 7) << 4);
            a[fm] = *(const short8*)(aubB + row * 512 + boff);
        }
        #pragma unroll
        for (int fn = 0; fn < 4; ++fn) {
            int ntile = wid * 4 + fn;
            b[fn] = *(const short8*)(WuP + ((size_t)(ntile * 8 + kk) * 64 + lane) * 8);
        }
        #pragma unroll
        for (int fm = 0; fm < 4; ++fm)
            #pragma unroll
            for (int fn = 0; fn < 4; ++fn)
                acc[fm][fn] = __builtin_amdgcn_mfma_f32_16x16x32_bf16(a[fm], b[fn], acc[fm][fn], 0, 0, 0);
    }

    float bu4[4];
    #pragma unroll
    for (int fn = 0; fn < 4; ++fn) bu4[fn] = bu[wid * 64 + fn * 16 + lr];

    #pragma unroll
    for (int fm = 0; fm < 4; ++fm) {
        #pragma unroll
        for (int i = 0; i < 4; ++i) {
            int r = base + fm * 16 + lk * 4 + i;
            if (r >= ncfg) continue;
            #pragma unroll
            for (int fn = 0; fn < 4; ++fn) {
                float p = acc[fm][fn][i] + bu4[fn];
                p = p > 0.f ? p : 0.f;
                projall[(size_t)r * D + wid * 64 + fn * 16 + lr] = f2bf(p);
            }
        }
    }
}

// Fused pass with role-split grid: (bid&7)==7 blocks stream the uncovered-row
// copy; others run the gather->GEMM2->mix->scatter tile. 512 threads.
// LDS (64KB) limits to 2 blocks/CU; launch_bounds(512,2) -> 128 VGPR cap (no spill).
__global__ __launch_bounds__(512, 2) void fused2m_kernel(
    const float* __restrict__ prev, const unsigned short* __restrict__ projall,
    const int* __restrict__ kidx, const int* __restrict__ vidx,
    const unsigned short* __restrict__ WgP, const float* __restrict__ bg,
    float* __restrict__ out, const unsigned char* __restrict__ flags,
    int ntiles, int nrows, int ncopywaves)
{
    __shared__ unsigned short Ast[64 * D];  // state bf16, swizzled 512B rows
    __shared__ unsigned short Apj[64 * D];  // proj  bf16, swizzled 512B rows
    char* astB = (char*)Ast;
    char* apjB = (char*)Apj;

    const int bid  = blockIdx.x;
    const int tid  = threadIdx.x;
    const int lane = tid & 63;
    const int wid  = tid >> 6;      // 0..7

    if ((bid & 7) == 7) {
        // ---- copy role: stream rows not covered by the scatter ----
        int cwave = (bid >> 3) * 8 + wid;
        const f32x4* src = (const f32x4*)prev;
        f32x4* dst = (f32x4*)out;
        for (int row = cwave; row < nrows; row += ncopywaves) {
            if (flags[row]) continue;
            size_t idx = (size_t)row * 64 + lane;
            f32x4 v = __builtin_nontemporal_load(src + idx);
            __builtin_nontemporal_store(v, dst + idx);
        }
        return;
    }

    const int tile = bid - (bid >> 3);
    if (tile >= ntiles) return;
    const int base = tile * 64;
    const int lr   = lane & 15;
    const int lk   = lane >> 4;

    // ---- stage state: 8 rows per wave, full-row coalesced f32x4 NT loads ----
    #pragma unroll
    for (int i = 0; i < 8; ++i) {
        int row = wid * 8 + i;
        int kr = kidx[base + row];
        f32x4 s = __builtin_nontemporal_load((const f32x4*)(prev + (size_t)kr * D) + lane);
        int boff = (lane * 8) ^ ((row & 7) << 4);
        u16x4 hs;
        hs.x = f2bf(s.x); hs.y = f2bf(s.y); hs.z = f2bf(s.z); hs.w = f2bf(s.w);
        *(u16x4*)(astB + row * 512 + boff) = hs;
    }
    // ---- stage proj: bf16 rows (512B), 2 rows per instruction, cached (reused) ----
    #pragma unroll
    for (int i = 0; i < 4; ++i) {
        int row = wid * 8 + i * 2 + (lane >> 5);
        int vr = vidx[base + row];
        short8 pv = *(const short8*)(projall + (size_t)vr * D + (lane & 31) * 8);
        int boff = ((lane & 31) * 16) ^ ((row & 7) << 4);
        *(short8*)(apjB + row * 512 + boff) = pv;
    }
    __syncthreads();

    // ---- GEMM2: logits = [state, proj] @ Wg, K = 512 ----
    f32x4 acc2[4][2];
    #pragma unroll
    for (int fm = 0; fm < 4; ++fm)
        #pragma unroll
        for (int fn = 0; fn < 2; ++fn)
            acc2[fm][fn] = (f32x4){0.f, 0.f, 0.f, 0.f};

    #pragma unroll
    for (int kk = 0; kk < 16; ++kk) {
        const char* Asrc = (kk < 8) ? astB : apjB;
        int kkl = kk & 7;
        short8 a[4], b[2];
        #pragma unroll
        for (int fm = 0; fm < 4; ++fm) {
            int row = fm * 16 + lr;
            int boff = (kkl * 64 + lk * 16) ^ ((row & 7) << 4);
            a[fm] = *(const short8*)(Asrc + row * 512 + boff);
        }
        #pragma unroll
        for (int fn = 0; fn < 2; ++fn) {
            int ntile = wid * 2 + fn;
            b[fn] = *(const short8*)(WgP + ((size_t)(ntile * 16 + kk) * 64 + lane) * 8);
        }
        #pragma unroll
        for (int fm = 0; fm < 4; ++fm)
            #pragma unroll
            for (int fn = 0; fn < 2; ++fn)
                acc2[fm][fn] = __builtin_amdgcn_mfma_f32_16x16x32_bf16(a[fm], b[fn], acc2[fm][fn], 0, 0, 0);
    }

    // ---- epilogue: gate = sigmoid(logits + bg); out = g*state + (1-g)*proj ----
    float bg2[2];
    #pragma unroll
    for (int fn = 0; fn < 2; ++fn) bg2[fn] = bg[wid * 32 + fn * 16 + lr];

    #pragma unroll
    for (int fm = 0; fm < 4; ++fm) {
        #pragma unroll
        for (int i = 0; i < 4; ++i) {
            int row = fm * 16 + lk * 4 + i;
            int kr = kidx[base + row];
            float* orow = out + (size_t)kr * D;
            #pragma unroll
            for (int fn = 0; fn < 2; ++fn) {
                int col = wid * 32 + fn * 16 + lr;
                float x = acc2[fm][fn][i] + bg2[fn];
                float g = 1.f / (1.f + __expf(-x));
                int boff = (col * 2) ^ ((row & 7) << 4);
                float st = bf2f(*(const unsigned short*)(astB + row * 512 + boff));
                float pj = bf2f(*(const unsigned short*)(apjB + row * 512 + boff));
                __builtin_nontemporal_store(g * st + (1.f - g) * pj, orow + col);
            }
        }
    }
}

extern "C" void kernel_launch(void* const* d_in, const int* in_sizes, int n_in,
                              void* d_out, int out_size, void* d_ws, size_t ws_size,
                              hipStream_t stream) {
    const float* prev = (const float*)d_in[0];
    const float* cfg  = (const float*)d_in[1];
    const int* kidx   = (const int*)d_in[2];
    const int* vidx   = (const int*)d_in[3];
    const float* Wu   = (const float*)d_in[4];
    const float* bu   = (const float*)d_in[5];
    const float* Wg   = (const float*)d_in[6];
    const float* bg   = (const float*)d_in[7];
    float* out = (float*)d_out;

    const int N_AST = in_sizes[0] / D;  // 500000
    const int N_CFG = in_sizes[1] / D;  // 100000
    const int M     = in_sizes[2];      // 400000

    unsigned short* WuP = (unsigned short*)d_ws;               // 128 KB
    unsigned short* WgP = WuP + 256 * 256;                     // 256 KB
    unsigned char* flags = (unsigned char*)(WgP + 512 * 256);  // N_AST bytes
    unsigned short* projall = (unsigned short*)((char*)d_ws + (1 << 20));  // N_CFG*256 bf16

    const int totalWu = 256 * 256;
    const int totalWg = 512 * 256;
    const int nflag4  = (N_AST + 3) / 4;
    const int ntiles  = M / 64;                       // 6250

    // role-split grid: one copy block per 8; need T - T/8 >= ntiles
    int total_blocks = (ntiles * 8 + 6) / 7;          // ceil(8/7 * ntiles)
    while (total_blocks - (total_blocks >> 3) < ntiles) ++total_blocks;
    const int ncopy = total_blocks >> 3;
    const int ncopywaves = ncopy * 8;

    pack_w_kernel<<<(totalWu + 255) / 256, 256, 0, stream>>>(Wu, WuP, 3, totalWu);
    pack_w_kernel<<<(totalWg + 255) / 256, 256, 0, stream>>>(Wg, WgP, 4, totalWg);
    clear_flags_kernel<<<(nflag4 + 255) / 256, 256, 0, stream>>>((unsigned*)flags, nflag4);
    scatter_flags_kernel<<<(M + 255) / 256, 256, 0, stream>>>(kidx, flags, M);

    projall_kernel<<<(N_CFG + 63) / 64, 256, 0, stream>>>(cfg, WuP, bu, projall, N_CFG);
    fused2m_kernel<<<total_blocks, 512, 0, stream>>>(prev, projall, kidx, vidx, WgP, bg,
                                                     out, flags, ntiles, N_AST, ncopywaves);
}

// Round 9
// 397.205 us; speedup vs baseline: 1.8193x; 1.8193x over previous
//
#include <hip/hip_runtime.h>
#include <hip/hip_bf16.h>

typedef __attribute__((ext_vector_type(8))) short short8;
typedef __attribute__((ext_vector_type(4))) float f32x4;
typedef __attribute__((ext_vector_type(4))) unsigned short u16x4;

#define D 256

static __device__ __forceinline__ unsigned short f2bf(float f) {
    union { __hip_bfloat16 h; unsigned short u; } v;
    v.h = __float2bfloat16(f);
    return v.u;
}
static __device__ __forceinline__ float bf2f(unsigned short h) {
    union { unsigned u; float f; } v; v.u = ((unsigned)h) << 16;
    return v.f;
}

// Pack W [K x 256] row-major f32 -> bf16 fragment-ready layout.
__global__ void pack_w_kernel(const float* __restrict__ W, unsigned short* __restrict__ dst,
                              int log2nkk, int total) {
    int p = blockIdx.x * blockDim.x + threadIdx.x;
    if (p >= total) return;
    int j     = p & 7;
    int lane  = (p >> 3) & 63;
    int kk    = (p >> 9) & ((1 << log2nkk) - 1);
    int ntile = p >> (9 + log2nkk);
    int k = kk * 32 + ((lane >> 4) * 8) + j;
    int n = ntile * 16 + (lane & 15);
    dst[p] = f2bf(W[k * D + n]);
}

__global__ void clear_flags_kernel(unsigned* __restrict__ f, int n) {
    int i = blockIdx.x * blockDim.x + threadIdx.x;
    if (i < n) f[i] = 0u;
}

__global__ void scatter_flags_kernel(const int* __restrict__ kidx,
                                     unsigned char* __restrict__ flags, int m) {
    int i = blockIdx.x * blockDim.x + threadIdx.x;
    if (i < m) flags[kidx[i]] = 1;
}

// projall[r] = relu(cfg[r] @ Wu + bu) as bf16, row-major [N_CFG][256].
__global__ __launch_bounds__(256, 5) void projall_kernel(
    const float* __restrict__ cfg, const unsigned short* __restrict__ WuP,
    const float* __restrict__ bu, unsigned short* __restrict__ projall, int ncfg)
{
    __shared__ unsigned short Aub[64 * D];
    char* aubB = (char*)Aub;
    const int t = threadIdx.x, lane = t & 63, wid = t >> 6;
    const int lr = lane & 15, lk = lane >> 4;
    const int base = blockIdx.x * 64;

    #pragma unroll
    for (int i = 0; i < 16; ++i) {
        int row = wid * 16 + i;
        int r = base + row;
        f32x4 u = (f32x4){0.f, 0.f, 0.f, 0.f};
        if (r < ncfg) u = *(const f32x4*)(cfg + (size_t)r * D + lane * 4);
        int boff = (lane * 8) ^ ((row & 7) << 4);
        u16x4 hu;
        hu.x = f2bf(u.x); hu.y = f2bf(u.y); hu.z = f2bf(u.z); hu.w = f2bf(u.w);
        *(u16x4*)(aubB + row * 512 + boff) = hu;
    }
    __syncthreads();

    f32x4 acc[4][4];
    #pragma unroll
    for (int fm = 0; fm < 4; ++fm)
        #pragma unroll
        for (int fn = 0; fn < 4; ++fn)
            acc[fm][fn] = (f32x4){0.f, 0.f, 0.f, 0.f};

    #pragma unroll
    for (int kk = 0; kk < 8; ++kk) {
        short8 a[4], b[4];
        #pragma unroll
        for (int fm = 0; fm < 4; ++fm) {
            int row = fm * 16 + lr;
            int boff = (kk * 64 + lk * 16) ^ ((row & 7) << 4);
            a[fm] = *(const short8*)(aubB + row * 512 + boff);
        }
        #pragma unroll
        for (int fn = 0; fn < 4; ++fn) {
            int ntile = wid * 4 + fn;
            b[fn] = *(const short8*)(WuP + ((size_t)(ntile * 8 + kk) * 64 + lane) * 8);
        }
        #pragma unroll
        for (int fm = 0; fm < 4; ++fm)
            #pragma unroll
            for (int fn = 0; fn < 4; ++fn)
                acc[fm][fn] = __builtin_amdgcn_mfma_f32_16x16x32_bf16(a[fm], b[fn], acc[fm][fn], 0, 0, 0);
    }

    float bu4[4];
    #pragma unroll
    for (int fn = 0; fn < 4; ++fn) bu4[fn] = bu[wid * 64 + fn * 16 + lr];

    #pragma unroll
    for (int fm = 0; fm < 4; ++fm) {
        #pragma unroll
        for (int i = 0; i < 4; ++i) {
            int r = base + fm * 16 + lk * 4 + i;
            if (r >= ncfg) continue;
            #pragma unroll
            for (int fn = 0; fn < 4; ++fn) {
                float p = acc[fm][fn][i] + bu4[fn];
                p = p > 0.f ? p : 0.f;
                projall[(size_t)r * D + wid * 64 + fn * 16 + lr] = f2bf(p);
            }
        }
    }
}

// GEMM2 fused pass: 1024 threads (16 waves), BM=64, each wave owns 64x16 cols.
// LDS 64KB -> 2 blocks/CU; launch_bounds(1024,8) pins <=64 VGPR so 32 waves/CU
// (100% occupancy) are resident. Tail: grid-stride copy of uncovered rows.
__global__ __launch_bounds__(1024, 8) void fused4_kernel(
    const float* __restrict__ prev, const unsigned short* __restrict__ projall,
    const int* __restrict__ kidx, const int* __restrict__ vidx,
    const unsigned short* __restrict__ WgP, const float* __restrict__ bg,
    float* __restrict__ out, const unsigned char* __restrict__ flags,
    int nrows, int rpb)
{
    __shared__ unsigned short Ast[64 * D];  // state bf16, swizzled 512B rows
    __shared__ unsigned short Apj[64 * D];  // proj  bf16, swizzled 512B rows
    char* astB = (char*)Ast;
    char* apjB = (char*)Apj;

    const int tid  = threadIdx.x;
    const int lane = tid & 63;
    const int wid  = tid >> 6;      // 0..15
    const int lr   = lane & 15;
    const int lk   = lane >> 4;
    const int base = blockIdx.x * 64;

    // ---- stage state: 4 rows per wave, full-row coalesced f32x4 NT loads ----
    #pragma unroll
    for (int i = 0; i < 4; ++i) {
        int row = wid * 4 + i;
        int kr = kidx[base + row];
        f32x4 s = __builtin_nontemporal_load((const f32x4*)(prev + (size_t)kr * D) + lane);
        int boff = (lane * 8) ^ ((row & 7) << 4);
        u16x4 hs;
        hs.x = f2bf(s.x); hs.y = f2bf(s.y); hs.z = f2bf(s.z); hs.w = f2bf(s.w);
        *(u16x4*)(astB + row * 512 + boff) = hs;
    }
    // ---- stage proj: bf16 rows (512B), 2 rows per instruction, cached (reused) ----
    #pragma unroll
    for (int i = 0; i < 2; ++i) {
        int row = wid * 4 + i * 2 + (lane >> 5);
        int vr = vidx[base + row];
        short8 pv = *(const short8*)(projall + (size_t)vr * D + (lane & 31) * 8);
        int boff = ((lane & 31) * 16) ^ ((row & 7) << 4);
        *(short8*)(apjB + row * 512 + boff) = pv;
    }
    __syncthreads();

    // ---- GEMM2: logits = [state, proj] @ Wg, K = 512; wave cols [wid*16, wid*16+16) ----
    f32x4 acc2[4];
    #pragma unroll
    for (int fm = 0; fm < 4; ++fm)
        acc2[fm] = (f32x4){0.f, 0.f, 0.f, 0.f};

    #pragma unroll
    for (int kk = 0; kk < 16; ++kk) {
        const char* Asrc = (kk < 8) ? astB : apjB;
        int kkl = kk & 7;
        short8 a[4], b;
        #pragma unroll
        for (int fm = 0; fm < 4; ++fm) {
            int row = fm * 16 + lr;
            int boff = (kkl * 64 + lk * 16) ^ ((row & 7) << 4);
            a[fm] = *(const short8*)(Asrc + row * 512 + boff);
        }
        b = *(const short8*)(WgP + ((size_t)(wid * 16 + kk) * 64 + lane) * 8);
        #pragma unroll
        for (int fm = 0; fm < 4; ++fm)
            acc2[fm] = __builtin_amdgcn_mfma_f32_16x16x32_bf16(a[fm], b, acc2[fm], 0, 0, 0);
    }

    // ---- epilogue: gate = sigmoid(logits + bg); out = g*state + (1-g)*proj ----
    const float bg1 = bg[wid * 16 + lr];
    const int col = wid * 16 + lr;

    #pragma unroll
    for (int fm = 0; fm < 4; ++fm) {
        #pragma unroll
        for (int i = 0; i < 4; ++i) {
            int row = fm * 16 + lk * 4 + i;
            int kr = kidx[base + row];
            float x = acc2[fm][i] + bg1;
            float g = 1.f / (1.f + __expf(-x));
            int boff = (col * 2) ^ ((row & 7) << 4);
            float st = bf2f(*(const unsigned short*)(astB + row * 512 + boff));
            float pj = bf2f(*(const unsigned short*)(apjB + row * 512 + boff));
            __builtin_nontemporal_store(g * st + (1.f - g) * pj, out + (size_t)kr * D + col);
        }
    }

    // ---- copy tail: this block's slice of uncovered rows (1KB NT row copies) ----
    int start = blockIdx.x * rpb;
    int end = start + rpb; if (end > nrows) end = nrows;
    for (int row = start + wid; row < end; row += 16) {
        if (flags[row]) continue;
        size_t idx = (size_t)row * 64 + lane;
        f32x4 v = __builtin_nontemporal_load((const f32x4*)prev + idx);
        __builtin_nontemporal_store(v, (f32x4*)out + idx);
    }
}

extern "C" void kernel_launch(void* const* d_in, const int* in_sizes, int n_in,
                              void* d_out, int out_size, void* d_ws, size_t ws_size,
                              hipStream_t stream) {
    const float* prev = (const float*)d_in[0];
    const float* cfg  = (const float*)d_in[1];
    const int* kidx   = (const int*)d_in[2];
    const int* vidx   = (const int*)d_in[3];
    const float* Wu   = (const float*)d_in[4];
    const float* bu   = (const float*)d_in[5];
    const float* Wg   = (const float*)d_in[6];
    const float* bg   = (const float*)d_in[7];
    float* out = (float*)d_out;

    const int N_AST = in_sizes[0] / D;  // 500000
    const int N_CFG = in_sizes[1] / D;  // 100000
    const int M     = in_sizes[2];      // 400000

    unsigned short* WuP = (unsigned short*)d_ws;               // 128 KB
    unsigned short* WgP = WuP + 256 * 256;                     // 256 KB
    unsigned char* flags = (unsigned char*)(WgP + 512 * 256);  // N_AST bytes
    unsigned short* projall = (unsigned short*)((char*)d_ws + (1 << 20));  // N_CFG*256 bf16

    const int totalWu = 256 * 256;
    const int totalWg = 512 * 256;
    const int nflag4  = (N_AST + 3) / 4;
    const int ntiles  = M / 64;                       // 6250
    const int rpb     = (N_AST + ntiles - 1) / ntiles; // 80

    pack_w_kernel<<<(totalWu + 255) / 256, 256, 0, stream>>>(Wu, WuP, 3, totalWu);
    pack_w_kernel<<<(totalWg + 255) / 256, 256, 0, stream>>>(Wg, WgP, 4, totalWg);
    clear_flags_kernel<<<(nflag4 + 255) / 256, 256, 0, stream>>>((unsigned*)flags, nflag4);
    scatter_flags_kernel<<<(M + 255) / 256, 256, 0, stream>>>(kidx, flags, M);

    projall_kernel<<<(N_CFG + 63) / 64, 256, 0, stream>>>(cfg, WuP, bu, projall, N_CFG);
    fused4_kernel<<<ntiles, 1024, 0, stream>>>(prev, projall, kidx, vidx, WgP, bg,
                                               out, flags, N_AST, rpb);
}